// Round 5
// baseline (1287.285 us; speedup 1.0000x reference)
//
#include <hip/hip_runtime.h>
#include <hip/hip_bf16.h>
#include <math.h>

#define BN    32
#define NTOK  785
#define GH    28
#define GW    28
#define DIM   768
#define QKVD  2304
#define NH    8
#define HD    96
#define MROWS (BN*NTOK)   // 25120

typedef __hip_bfloat16 bf16;
typedef unsigned short ushort_t;
typedef short s16x8 __attribute__((ext_vector_type(8)));   // 8 bf16 = 4 VGPRs
typedef float f32x4 __attribute__((ext_vector_type(4)));   // MFMA acc

// ---------------------------------------------------------------------------
// helpers
// ---------------------------------------------------------------------------
__device__ __forceinline__ void gl2lds16(const void* g, void* l) {
    // 16B per lane, LDS dest = wave-uniform base + lane*16
    __builtin_amdgcn_global_load_lds(
        (__attribute__((address_space(1))) void*)const_cast<void*>(g),
        (__attribute__((address_space(3))) void*)l, 16, 0, 0);
}

__device__ __forceinline__ ushort_t f2bf(float f) {
    bf16 h = __float2bfloat16(f);
    return *(ushort_t*)&h;
}

__device__ __forceinline__ s16x8 cvt8_2(const float* p0, const float* p1) {
    float4 a = *(const float4*)p0;
    float4 b = *(const float4*)p1;
    union { s16x8 v; __hip_bfloat162 h[4]; } r;
    r.h[0] = __float22bfloat162_rn(make_float2(a.x, a.y));
    r.h[1] = __float22bfloat162_rn(make_float2(a.z, a.w));
    r.h[2] = __float22bfloat162_rn(make_float2(b.x, b.y));
    r.h[3] = __float22bfloat162_rn(make_float2(b.z, b.w));
    return r.v;
}

// ---------------------------------------------------------------------------
// K0: transpose-convert W[R][C] fp32 -> Wt[C][R] bf16
// ---------------------------------------------------------------------------
__global__ __launch_bounds__(256)
void transpose_bf16_kernel(const float* __restrict__ W, ushort_t* __restrict__ Wt,
                           int R, int C) {
    __shared__ float tile[32][33];
    int c0 = blockIdx.x * 32, r0 = blockIdx.y * 32;
    int tx = threadIdx.x, ty = threadIdx.y;   // 32 x 8
    #pragma unroll
    for (int i = 0; i < 4; ++i)
        tile[ty + i * 8][tx] = W[(size_t)(r0 + ty + i * 8) * C + c0 + tx];
    __syncthreads();
    #pragma unroll
    for (int i = 0; i < 4; ++i)
        Wt[(size_t)(c0 + ty + i * 8) * R + r0 + tx] = f2bf(tile[tx][ty + i * 8]);
}

// ---------------------------------------------------------------------------
// K1: qkv GEMM via MFMA, 128x128 tile, BK=32, 4 waves.
// LDS in FRAGMENT ORDER (conflict-free ds_read_b128: lane -> base+lane*16):
//   A (fp32, subtile 16m x 32k = 2048B): blk(m,kb4f) at s*2048+(kb&1)*1024+(kb>>1)*256+m*16
//   B (bf16, subtile 16n x 32k = 1024B): blk(n,kb8h) at s*1024+kb*256+n*16
// ---------------------------------------------------------------------------
__global__ __launch_bounds__(256)
void gemm_qkv_mfma(const float* __restrict__ A, const ushort_t* __restrict__ Bt,
                   const float* __restrict__ bias,
                   ushort_t* __restrict__ q, ushort_t* __restrict__ kk,
                   ushort_t* __restrict__ v) {
    const int M = MROWS, K = DIM;
    __shared__ float    Asm[128 * 32];   // 16 KB
    __shared__ ushort_t Bsm[128 * 32];   //  8 KB
    const int tid  = threadIdx.x;
    const int wave = tid >> 6;
    const int lane = tid & 63;
    const int row0 = blockIdx.y * 128;
    const int col0 = blockIdx.x * 128;
    const int wm = wave >> 1, wn = wave & 1;
    const int q4 = lane >> 4, l15 = lane & 15;

    f32x4 acc[4][4];
    #pragma unroll
    for (int i = 0; i < 4; ++i)
        #pragma unroll
        for (int j = 0; j < 4; ++j) acc[i][j] = (f32x4){0.f, 0.f, 0.f, 0.f};

    for (int kt = 0; kt < K; kt += 32) {
        // --- stage A: 16 instrs; idx = r*4+wave; s=idx>>1, hb=idx&1 ---
        #pragma unroll
        for (int r = 0; r < 4; ++r) {
            int idx = r * 4 + wave;
            int s = idx >> 1, hb = idx & 1;
            int grow = min(row0 + s * 16 + l15, M - 1);
            const float* gp = A + (size_t)grow * K + kt + q4 * 8 + hb * 4;
            gl2lds16(gp, &Asm[s * 512 + hb * 256]);
        }
        // --- stage B: 8 instrs; seg = r*4+wave ---
        #pragma unroll
        for (int r = 0; r < 2; ++r) {
            int seg = r * 4 + wave;
            const ushort_t* gp = Bt + (size_t)(col0 + seg * 16 + l15) * K + kt + q4 * 8;
            gl2lds16(gp, &Bsm[seg * 512]);
        }
        __syncthreads();
        s16x8 af[4], bfr[4];
        #pragma unroll
        for (int mi = 0; mi < 4; ++mi) {
            int s = wm * 4 + mi;
            af[mi] = cvt8_2(&Asm[s * 512 + q4 * 64 + l15 * 4],
                            &Asm[s * 512 + 256 + q4 * 64 + l15 * 4]);
        }
        #pragma unroll
        for (int ni = 0; ni < 4; ++ni) {
            int s = wn * 4 + ni;
            bfr[ni] = *(const s16x8*)&Bsm[s * 512 + q4 * 128 + l15 * 8];
        }
        #pragma unroll
        for (int mi = 0; mi < 4; ++mi)
            #pragma unroll
            for (int ni = 0; ni < 4; ++ni)
                acc[mi][ni] = __builtin_amdgcn_mfma_f32_16x16x32_bf16(
                    af[mi], bfr[ni], acc[mi][ni], 0, 0, 0);
        __syncthreads();
    }
    int colbase = col0 + wn * 64;
    int seg = colbase / DIM;
    int csub = colbase - seg * DIM;
    ushort_t* outp = (seg == 0) ? q : (seg == 1) ? kk : v;
    #pragma unroll
    for (int mi = 0; mi < 4; ++mi) {
        #pragma unroll
        for (int ni = 0; ni < 4; ++ni) {
            int gcol = colbase + ni * 16 + l15;
            int col  = csub + ni * 16 + l15;
            float bb = bias[gcol];
            #pragma unroll
            for (int j = 0; j < 4; ++j) {
                int row = row0 + wm * 64 + mi * 16 + q4 * 4 + j;
                if (row < M)
                    outp[(size_t)row * DIM + col] = f2bf(acc[mi][ni][j] + bb);
            }
        }
    }
}

// ---------------------------------------------------------------------------
// K6: out GEMM via MFMA, fragment-order LDS both sides (bf16).
// ---------------------------------------------------------------------------
__global__ __launch_bounds__(256)
void gemm_out_mfma(const ushort_t* __restrict__ A, const ushort_t* __restrict__ Bt,
                   const float* __restrict__ bias, float* __restrict__ C) {
    const int M = MROWS, N = DIM, K = DIM;
    __shared__ ushort_t Asm[128 * 32];
    __shared__ ushort_t Bsm[128 * 32];
    const int tid  = threadIdx.x;
    const int wave = tid >> 6;
    const int lane = tid & 63;
    const int row0 = blockIdx.y * 128;
    const int col0 = blockIdx.x * 128;
    const int wm = wave >> 1, wn = wave & 1;
    const int q4 = lane >> 4, l15 = lane & 15;

    f32x4 acc[4][4];
    #pragma unroll
    for (int i = 0; i < 4; ++i)
        #pragma unroll
        for (int j = 0; j < 4; ++j) acc[i][j] = (f32x4){0.f, 0.f, 0.f, 0.f};

    for (int kt = 0; kt < K; kt += 32) {
        #pragma unroll
        for (int r = 0; r < 2; ++r) {
            int seg = r * 4 + wave;
            int grow = min(row0 + seg * 16 + l15, M - 1);
            const ushort_t* gp = A + (size_t)grow * K + kt + q4 * 8;
            gl2lds16(gp, &Asm[seg * 512]);
        }
        #pragma unroll
        for (int r = 0; r < 2; ++r) {
            int seg = r * 4 + wave;
            const ushort_t* gp = Bt + (size_t)(col0 + seg * 16 + l15) * K + kt + q4 * 8;
            gl2lds16(gp, &Bsm[seg * 512]);
        }
        __syncthreads();
        s16x8 af[4], bfr[4];
        #pragma unroll
        for (int mi = 0; mi < 4; ++mi)
            af[mi] = *(const s16x8*)&Asm[(wm * 4 + mi) * 512 + q4 * 128 + l15 * 8];
        #pragma unroll
        for (int ni = 0; ni < 4; ++ni)
            bfr[ni] = *(const s16x8*)&Bsm[(wn * 4 + ni) * 512 + q4 * 128 + l15 * 8];
        #pragma unroll
        for (int mi = 0; mi < 4; ++mi)
            #pragma unroll
            for (int ni = 0; ni < 4; ++ni)
                acc[mi][ni] = __builtin_amdgcn_mfma_f32_16x16x32_bf16(
                    af[mi], bfr[ni], acc[mi][ni], 0, 0, 0);
        __syncthreads();
    }
    #pragma unroll
    for (int mi = 0; mi < 4; ++mi) {
        #pragma unroll
        for (int ni = 0; ni < 4; ++ni) {
            int col = col0 + wn * 64 + ni * 16 + l15;
            float bb = bias[col];
            #pragma unroll
            for (int j = 0; j < 4; ++j) {
                int row = row0 + wm * 64 + mi * 16 + q4 * 4 + j;
                if (row < M)
                    C[(size_t)row * N + col] = acc[mi][ni][j] + bb;
            }
        }
    }
}

// ---------------------------------------------------------------------------
// K2: per-(b,c) softmax stats over 785 tokens of k
// ---------------------------------------------------------------------------
__global__ __launch_bounds__(256)
void softmax_stats_kernel(const bf16* __restrict__ k,
                          float* __restrict__ stat_m, float* __restrict__ stat_is) {
    int b = blockIdx.y;
    int c = blockIdx.x * 64 + threadIdx.x;
    int ty = threadIdx.y;
    const bf16* base = k + (size_t)b * NTOK * DIM + c;
    float m = -1e30f, s = 0.f;
    for (int n = ty; n < NTOK; n += 4) {
        float kv = __bfloat162float(base[(size_t)n * DIM]);
        float nm = fmaxf(m, kv);
        s = s * __expf(m - nm) + __expf(kv - nm);
        m = nm;
    }
    __shared__ float sm[4][64], ss[4][64];
    sm[ty][threadIdx.x] = m; ss[ty][threadIdx.x] = s;
    __syncthreads();
    if (ty == 0) {
        float M = sm[0][threadIdx.x];
        #pragma unroll
        for (int i = 1; i < 4; ++i) M = fmaxf(M, sm[i][threadIdx.x]);
        float S = 0.f;
        #pragma unroll
        for (int i = 0; i < 4; ++i) S += ss[i][threadIdx.x] * __expf(sm[i][threadIdx.x] - M);
        stat_m[b * DIM + c] = M;
        stat_is[b * DIM + c] = 1.f / S;
    }
}

// ---------------------------------------------------------------------------
// K3: attn[b,h,d,e] = sum_n softmax(k)[n,d] * v[n,e]
// ---------------------------------------------------------------------------
__global__ __launch_bounds__(256)
void attn_kernel(const bf16* __restrict__ k, const bf16* __restrict__ v,
                 const float* __restrict__ stat_m, const float* __restrict__ stat_is,
                 float* __restrict__ attn) {
    int h = blockIdx.x, b = blockIdx.y;
    int tx = threadIdx.x, ty = threadIdx.y;
    int t = ty * 16 + tx;
    __shared__ float ek[16][96], vv[16][96];
    __shared__ float smM[96], smIS[96];
    if (t < 96) { smM[t] = stat_m[b * DIM + h * HD + t]; smIS[t] = stat_is[b * DIM + h * HD + t]; }
    __syncthreads();
    float acc[6][6] = {};
    const bf16* kbase = k + (size_t)b * NTOK * DIM + h * HD;
    const bf16* vbase = v + (size_t)b * NTOK * DIM + h * HD;
    for (int n0 = 0; n0 < NTOK; n0 += 16) {
        #pragma unroll
        for (int i = 0; i < 6; ++i) {
            int idx = t + i * 256;
            int nl = idx / 96, c = idx % 96;
            int n = n0 + nl;
            float ekv = 0.f, vvv = 0.f;
            if (n < NTOK) {
                float kv = __bfloat162float(kbase[(size_t)n * DIM + c]);
                ekv = __expf(kv - smM[c]) * smIS[c];
                vvv = __bfloat162float(vbase[(size_t)n * DIM + c]);
            }
            ek[nl][c] = ekv; vv[nl][c] = vvv;
        }
        __syncthreads();
        #pragma unroll
        for (int nl = 0; nl < 16; ++nl) {
            float ka[6], vb[6];
            #pragma unroll
            for (int i = 0; i < 6; ++i) ka[i] = ek[nl][tx * 6 + i];
            #pragma unroll
            for (int j = 0; j < 6; ++j) vb[j] = vv[nl][ty * 6 + j];
            #pragma unroll
            for (int i = 0; i < 6; ++i)
                #pragma unroll
                for (int j = 0; j < 6; ++j)
                    acc[i][j] += ka[i] * vb[j];
        }
        __syncthreads();
    }
    float* abase = attn + ((size_t)(b * NH + h)) * HD * HD;
    #pragma unroll
    for (int i = 0; i < 6; ++i)
        #pragma unroll
        for (int j = 0; j < 6; ++j)
            abase[(size_t)(tx * 6 + i) * HD + ty * 6 + j] = acc[i][j];
}

// ---------------------------------------------------------------------------
// K4: CRPE depthwise conv, LDS-staged.
// ---------------------------------------------------------------------------
template<int KS>
__device__ __forceinline__ void crpe_conv(const ushort_t* vimg, const float* wp,
                                          float bias0, float bias1,
                                          ushort_t* ob, int chp, int yq,
                                          int hf, int rowlo) {
    constexpr int R = KS / 2;
    float wA[KS * KS], wB[KS * KS];
    #pragma unroll
    for (int i = 0; i < KS * KS; ++i) { wA[i] = wp[i]; wB[i] = wp[KS * KS + i]; }
    #pragma unroll
    for (int yy0 = 0; yy0 < 2; ++yy0) {
        int yl = yq + yy0 * 8;
        if (yl >= 14) break;
        int y = hf * 14 + yl;
        for (int x = 0; x < GW; ++x) {
            float a0 = bias0, a1 = bias1;
            #pragma unroll
            for (int ky = 0; ky < KS; ++ky) {
                int gy = y + ky - R;
                if (gy < 0 || gy >= GH) continue;
                int ly = gy - rowlo;
                #pragma unroll
                for (int kx = 0; kx < KS; ++kx) {
                    int xx = x + kx - R;
                    if (xx < 0 || xx >= GW) continue;
                    __hip_bfloat162 pv =
                        *(const __hip_bfloat162*)&vimg[(ly * 28 + xx) * 64 + chp * 2];
                    float2 f = __bfloat1622float2(pv);
                    a0 = fmaf(wA[ky * KS + kx], f.x, a0);
                    a1 = fmaf(wB[ky * KS + kx], f.y, a1);
                }
            }
            *(__hip_bfloat162*)&ob[(size_t)(1 + y * GW + x) * DIM + chp * 2] =
                __float22bfloat162_rn(make_float2(a0, a1));
        }
    }
}

__global__ __launch_bounds__(256)
void crpe_lds_kernel(const ushort_t* __restrict__ v,
                     const float* __restrict__ w3, const float* __restrict__ b3,
                     const float* __restrict__ w5, const float* __restrict__ b5,
                     const float* __restrict__ w7, const float* __restrict__ b7,
                     ushort_t* __restrict__ o) {
    __shared__ ushort_t vimg[17 * 28 * 64];   // 60928 B
    const int cg  = blockIdx.x;
    const int hf  = blockIdx.y;
    const int b   = blockIdx.z;
    const int tid = threadIdx.x;
    const int c0  = cg * 64;
    const int rowlo = hf ? 11 : 0;

    const ushort_t* vb = v + (size_t)b * NTOK * DIM + c0;
    for (int idx = tid; idx < 17 * 28 * 8; idx += 256) {
        int p8 = idx >> 3, c8 = idx & 7;
        int pix = rowlo * 28 + p8;
        *(s16x8*)&vimg[p8 * 64 + c8 * 8] =
            *(const s16x8*)(vb + (size_t)(1 + pix) * DIM + c8 * 8);
    }
    ushort_t* ob = o + (size_t)b * NTOK * DIM + c0;
    if (hf == 0 && tid < 64) ob[tid] = 0;
    __syncthreads();

    const int chp = tid & 31;
    const int yq  = tid >> 5;
    const int ch0 = c0 + chp * 2;
    if (ch0 < 192)
        crpe_conv<3>(vimg, w3 + ch0 * 9, b3[ch0], b3[ch0 + 1], ob, chp, yq, hf, rowlo);
    else if (ch0 < 480)
        crpe_conv<5>(vimg, w5 + (ch0 - 192) * 25, b5[ch0 - 192], b5[ch0 - 191],
                     ob, chp, yq, hf, rowlo);
    else
        crpe_conv<7>(vimg, w7 + (ch0 - 480) * 49, b7[ch0 - 480], b7[ch0 - 479],
                     ob, chp, yq, hf, rowlo);
}

// ---------------------------------------------------------------------------
// K5: o[b,n,h*96+e] = scale * sum_d q[n,d] attn[d,e] + q[n,e] * rp (in-place)
// ---------------------------------------------------------------------------
__global__ __launch_bounds__(256)
void combine_kernel(const bf16* __restrict__ q, const float* __restrict__ attn,
                    bf16* __restrict__ o) {
    int h = blockIdx.x;
    int n0 = blockIdx.y * 64;
    int b = blockIdx.z;
    int tx = threadIdx.x, ty = threadIdx.y;
    int t = ty * 16 + tx;
    __shared__ float as[96][96];
    __shared__ float qs[64][97];
    const float* abase = attn + ((size_t)(b * NH + h)) * HD * HD;
    #pragma unroll
    for (int i = 0; i < 36; ++i) {
        int idx = t + i * 256;
        as[idx / 96][idx % 96] = abase[idx];
    }
    const bf16* qbase = q + (size_t)b * NTOK * DIM + h * HD;
    #pragma unroll
    for (int i = 0; i < 24; ++i) {
        int idx = t + i * 256;
        int rr = idx / 96, cc = idx % 96;
        int n = n0 + rr;
        qs[rr][cc] = (n < NTOK) ? __bfloat162float(qbase[(size_t)n * DIM + cc]) : 0.f;
    }
    __syncthreads();
    float acc[4][6] = {};
    for (int d = 0; d < 96; ++d) {
        float qa[4], ab[6];
        #pragma unroll
        for (int i = 0; i < 4; ++i) qa[i] = qs[ty * 4 + i][d];
        #pragma unroll
        for (int j = 0; j < 6; ++j) ab[j] = as[d][tx * 6 + j];
        #pragma unroll
        for (int i = 0; i < 4; ++i)
            #pragma unroll
            for (int j = 0; j < 6; ++j)
                acc[i][j] += qa[i] * ab[j];
    }
    const float scale = 0.10206207261596575f;  // 96^-0.5
    bf16* obase = o + (size_t)b * NTOK * DIM + h * HD;
    #pragma unroll
    for (int i = 0; i < 4; ++i) {
        int n = n0 + ty * 4 + i;
        if (n >= NTOK) continue;
        #pragma unroll
        for (int j = 0; j < 6; ++j) {
            int e = tx * 6 + j;
            size_t oa = (size_t)n * DIM + e;
            float rp = __bfloat162float(obase[oa]);
            float qv = qs[ty * 4 + i][e];
            obase[oa] = __float2bfloat16(scale * acc[i][j] + qv * rp);
        }
    }
}

// ---------------------------------------------------------------------------
extern "C" void kernel_launch(void* const* d_in, const int* in_sizes, int n_in,
                              void* d_out, int out_size, void* d_ws, size_t ws_size,
                              hipStream_t stream) {
    const float* x     = (const float*)d_in[0];
    const float* W_qkv = (const float*)d_in[1];
    const float* b_qkv = (const float*)d_in[2];
    const float* W_out = (const float*)d_in[3];
    const float* b_out = (const float*)d_in[4];
    const float* w3    = (const float*)d_in[5];
    const float* cb3   = (const float*)d_in[6];
    const float* w5    = (const float*)d_in[7];
    const float* cb5   = (const float*)d_in[8];
    const float* w7    = (const float*)d_in[9];
    const float* cb7   = (const float*)d_in[10];
    float* out = (float*)d_out;

    ushort_t* q = (ushort_t*)d_ws;
    ushort_t* k = q + (size_t)MROWS * DIM;
    ushort_t* v = k + (size_t)MROWS * DIM;
    float* attn    = (float*)(v + (size_t)MROWS * DIM);
    float* stat_m  = attn + (size_t)BN * NH * HD * HD;
    float* stat_is = stat_m + (size_t)BN * DIM;
    ushort_t* Wqkvt = (ushort_t*)(stat_is + (size_t)BN * DIM);
    ushort_t* Wot   = Wqkvt + (size_t)QKVD * DIM;
    ushort_t* o = k;   // alias: k dead after attn_kernel

    transpose_bf16_kernel<<<dim3(QKVD / 32, DIM / 32), dim3(32, 8), 0, stream>>>(
        W_qkv, Wqkvt, DIM, QKVD);
    transpose_bf16_kernel<<<dim3(DIM / 32, DIM / 32), dim3(32, 8), 0, stream>>>(
        W_out, Wot, DIM, DIM);
    gemm_qkv_mfma<<<dim3(QKVD / 128, (MROWS + 127) / 128), 256, 0, stream>>>(
        x, Wqkvt, b_qkv, q, k, v);
    softmax_stats_kernel<<<dim3(12, BN), dim3(64, 4), 0, stream>>>(
        (const bf16*)k, stat_m, stat_is);
    attn_kernel<<<dim3(NH, BN), dim3(16, 16), 0, stream>>>(
        (const bf16*)k, (const bf16*)v, stat_m, stat_is, attn);
    crpe_lds_kernel<<<dim3(12, 2, BN), 256, 0, stream>>>(
        v, w3, cb3, w5, cb5, w7, cb7, o);
    combine_kernel<<<dim3(NH, 13, BN), dim3(16, 16), 0, stream>>>(
        (const bf16*)q, attn, (bf16*)o);
    gemm_out_mfma<<<dim3(DIM / 128, (MROWS + 127) / 128), 256, 0, stream>>>(
        o, Wot, b_out, out);
}